// Round 8
// baseline (3025.669 us; speedup 1.0000x reference)
//
#include <hip/hip_runtime.h>
#include <hip/hip_fp16.h>

// Problem dims
constexpr int kT = 512, kB = 32, kD = 512, kH = 256, kA1 = 16, kA2 = 128;
constexpr int kNPeer = 8, kSlice = 32;   // kNPeer * kSlice == kH

typedef _Float16 h2_t __attribute__((ext_vector_type(2)));
typedef _Float16 h8_t __attribute__((ext_vector_type(8)));
typedef unsigned u4_t __attribute__((ext_vector_type(4)));

#if defined(__has_builtin)
#if __has_builtin(__builtin_amdgcn_fdot2)
#define HAVE_FDOT2 1
#endif
#endif

__device__ __forceinline__ float fast_tanh(float x) {
    // tanh(x) = 1 - 2/(exp(2x)+1); exp overflow -> inf -> 2/inf=0 -> 1 (correct)
    float e = __expf(2.0f * x);
    return 1.0f - 2.0f / (e + 1.0f);
}
__device__ __forceinline__ float fast_sig(float x) {
    return 1.0f / (1.0f + __expf(-x));
}

__device__ __forceinline__ float dot_pair(h2_t w, h2_t h, float acc) {
#if defined(HAVE_FDOT2)
    return __builtin_amdgcn_fdot2(w, h, acc, false);
#else
    acc = fmaf((float)w[0], (float)h[0], acc);
    return fmaf((float)w[1], (float)h[1], acc);
#endif
}

// ---------------- Kernel 1: attention over feature axis D -> seq (T,B) -------
__global__ __launch_bounds__(256) void att1_kernel(
    const float* __restrict__ x, const float* __restrict__ W1,
    const float* __restrict__ b1, const float* __restrict__ u1,
    float* __restrict__ seq) {
    int blk = blockIdx.x;                 // t*32 + b ; x offset = blk*kD
    int tid = threadIdx.x;
    const float* xp = x + (size_t)blk * kD;
    float x0 = xp[tid], x1 = xp[tid + 256];
    float s0 = 0.f, s1 = 0.f;
#pragma unroll
    for (int a = 0; a < kA1; ++a) {
        float w = W1[a], bb = b1[a], uu = u1[a];
        s0 += fast_tanh(fmaf(x0, w, bb)) * uu;
        s1 += fast_tanh(fmaf(x1, w, bb)) * uu;
    }
    float e0 = __expf(s0), e1 = __expf(s1);
    float se = e0 + e1;
    float sxe = fmaf(x0, e0, x1 * e1);
#pragma unroll
    for (int m = 32; m; m >>= 1) {
        se  += __shfl_xor(se,  m, 64);
        sxe += __shfl_xor(sxe, m, 64);
    }
    __shared__ float r_se[4], r_sxe[4];
    int wave = tid >> 6, lane = tid & 63;
    if (lane == 0) { r_se[wave] = se; r_sxe[wave] = sxe; }
    __syncthreads();
    if (tid == 0) {
        float S = r_se[0] + r_se[1] + r_se[2] + r_se[3];
        float X = r_sxe[0] + r_sxe[1] + r_sxe[2] + r_sxe[3];
        seq[blk] = X / S;
    }
}

// ------------- Kernel 1b: convert W_hh (4H,H) fp32 -> packed fp16 ------------
// Layout (half units): WQ[kk4*8192 + j*8 + q*2 + {0,1}] = W_hh[j][2*(4*kk4+q) + {0,1}]
// => as 16B vectors: W4[kk4*1024 + j] holds 8 consecutive k for row j.
__global__ __launch_bounds__(256) void wconv_kernel(
    const float* __restrict__ Whh, _Float16* __restrict__ WQ) {
    int idx = blockIdx.x * 256 + threadIdx.x;   // 0..131071 = j*128 + kk
    int j = idx >> 7, kk = idx & 127;
    int kk4 = kk >> 2, q = kk & 3;
    float a = Whh[j * kH + 2 * kk];
    float b = Whh[j * kH + 2 * kk + 1];
    _Float16* dst = WQ + ((size_t)kk4 * 8192 + j * 8 + q * 2);
    dst[0] = (_Float16)a;
    dst[1] = (_Float16)b;
}

// ---------------- Kernel 2: multi-block-per-batch LSTM -----------------------
// Grid = kB*kNPeer blocks, 256 threads each (all 256 CUs). Peer p of batch b
// owns h-slice [p*32, p*32+32): 128 gate rows (all 4 gates of its slice ->
// block-local c/h update). Its 64 KB weight sub-matrix is FULLY LDS-RESIDENT
// (r2/r5/r6/r7 evidence: the allocator refuses VGPR residency for big
// loop-invariant slabs -> stop fighting it; LDS can't be evicted).
// Per-step weight traffic from L2: zero (was 384 KB/CU/step, the bound).
//
// Cross-block recurrence: peers exchange h through hs with the standard
// flag idiom: relaxed agent-scope atomic h stores + release fetch_add on
// cnt[t][b]; consumers acquire-spin then relaxed atomic loads. Peers of a
// batch are blockIdx = p*32+b -> likely same XCD (perf-only; correctness
// from agent scope). Deadlock-safe: 67 KB LDS -> 2 blocks/CU capacity = 512
// >= 256 blocks, all co-resident. cnt zeroed per launch via hipMemsetAsync.
//
// Thread map: w=tid>>6, l=tid&63; half=w&1 (k-range), r=(w>>1)*64+l (local
// row 0..127); global gate row = (r>>5)*256 + p*32 + (r&31). half is
// wave-uniform so the readlane h-broadcast selector is uniform (required).
#define HP(KK) __builtin_bit_cast(h2_t, (unsigned)__builtin_amdgcn_readlane((int)hsel, (KK)))
#define DOT4S(W, KKB) do { \
    acc = dot_pair(__builtin_shufflevector((W), (W), 0, 1), HP((KKB) + 0), acc); \
    acc = dot_pair(__builtin_shufflevector((W), (W), 2, 3), HP((KKB) + 1), acc); \
    acc = dot_pair(__builtin_shufflevector((W), (W), 4, 5), HP((KKB) + 2), acc); \
    acc = dot_pair(__builtin_shufflevector((W), (W), 6, 7), HP((KKB) + 3), acc); \
} while (0)

__global__ __launch_bounds__(256) void lstm_kernel(
    const float* __restrict__ seq, const _Float16* __restrict__ WQ,
    const float* __restrict__ W_ih, const float* __restrict__ b_ih,
    const float* __restrict__ b_hh, const float* __restrict__ h0,
    const float* __restrict__ c0, float* __restrict__ hs,
    unsigned* __restrict__ cnt) {
    int bid = blockIdx.x;
    int b = bid & 31;            // batch
    int p = bid >> 5;            // peer 0..7
    int tid = threadIdx.x;
    int w = tid >> 6, l = tid & 63;
    int half = w & 1;                       // k-half (wave-uniform)
    int r = (w >> 1) * 64 + l;              // local row 0..127
    int grow = (r >> 5) * 256 + p * kSlice + (r & 31);  // global gate row

    __shared__ float seq_l[kT];                     // 2 KB
    __shared__ __align__(16) u4_t wlds[16 * 256];   // 64 KB weight slab
    __shared__ float gl[256];                       // 1 KB half-dots

    const u4_t* W4 = (const u4_t*)WQ;
    // stage this block's weights once: thread covers 16 quads (k-half of row)
#pragma unroll
    for (int q = 0; q < 16; ++q)
        wlds[q * 256 + tid] = W4[(half * 16 + q) * 1024 + grow];

    for (int t = tid; t < kT; t += 256) seq_l[t] = seq[t * kB + b];

    float wih  = W_ih[grow];
    float bias = b_ih[grow] + b_hh[grow];
    float c = (tid < kSlice) ? c0[b * kH + p * kSlice + tid] : 0.f;
    __syncthreads();

#pragma unroll 1
    for (int t = 0; t < kT; ++t) {
        if (t > 0) {
            if (tid == 0) {
                while (__hip_atomic_load(&cnt[(t - 1) * kB + b],
                           __ATOMIC_ACQUIRE, __HIP_MEMORY_SCOPE_AGENT) < (unsigned)kNPeer)
                    __builtin_amdgcn_s_sleep(1);
            }
            __syncthreads();
        }
        // load h (fp32) -> packed fp16 pairs, one per lane slot
        const float* hsrc = (t == 0) ? (h0 + b * kH)
                                     : (hs + (size_t)(t - 1) * (kB * kH) + b * kH);
        const unsigned long long* h64 = (const unsigned long long*)hsrc;
        unsigned long long v0 = __hip_atomic_load(h64 + l,      __ATOMIC_RELAXED, __HIP_MEMORY_SCOPE_AGENT);
        unsigned long long v1 = __hip_atomic_load(h64 + 64 + l, __ATOMIC_RELAXED, __HIP_MEMORY_SCOPE_AGENT);
        float2 f0 = __builtin_bit_cast(float2, v0);
        float2 f1 = __builtin_bit_cast(float2, v1);
        h2_t p0; p0[0] = (_Float16)f0.x; p0[1] = (_Float16)f0.y;
        h2_t p1; p1[0] = (_Float16)f1.x; p1[1] = (_Float16)f1.y;
        unsigned hr0 = __builtin_bit_cast(unsigned, p0);   // pair[l]
        unsigned hr1 = __builtin_bit_cast(unsigned, p1);   // pair[64+l]
        unsigned hsel = half ? hr1 : hr0;                  // wave-uniform select

        float acc = (half == 0) ? fmaf(seq_l[t], wih, bias) : 0.f;
#pragma unroll
        for (int q = 0; q < 16; ++q) {
            h8_t wv = __builtin_bit_cast(h8_t, wlds[q * 256 + tid]);
            DOT4S(wv, q * 4);
        }
        gl[tid] = acc;
        __syncthreads();

        if (tid < kSlice) {
            float s_i = gl[tid]       + gl[64 + tid];
            float s_f = gl[32 + tid]  + gl[96 + tid];
            float s_g = gl[128 + tid] + gl[192 + tid];
            float s_o = gl[160 + tid] + gl[224 + tid];
            float ig = fast_sig(s_i), fg = fast_sig(s_f);
            float gg = fast_tanh(s_g), og = fast_sig(s_o);
            c = fmaf(fg, c, ig * gg);
            float h = og * fast_tanh(c);
            __hip_atomic_store(
                (unsigned*)(hs + (size_t)t * (kB * kH) + b * kH + p * kSlice + tid),
                __builtin_bit_cast(unsigned, h),
                __ATOMIC_RELAXED, __HIP_MEMORY_SCOPE_AGENT);
        }
        if (tid == 0)
            __hip_atomic_fetch_add(&cnt[t * kB + b], 1u,
                                   __ATOMIC_RELEASE, __HIP_MEMORY_SCOPE_AGENT);
        __syncthreads();   // WAR on gl before next iteration
    }
}

// ---------------- Kernel 3a: attention-2 scores e2 (T,B) ---------------------
// Block = (b, chunk of 16 t). 128 threads, thread a owns attention unit a.
__global__ __launch_bounds__(128) void att2a_kernel(
    const float* __restrict__ hs, const float* __restrict__ W2,
    const float* __restrict__ b2, const float* __restrict__ u2,
    float* __restrict__ a2w) {
    int b  = blockIdx.x & 31;
    int tc = blockIdx.x >> 5;   // 0..31
    int a  = threadIdx.x;       // 0..127
    __shared__ __align__(16) float hl[16][kH];
    __shared__ float red[16][2];
    int t0 = tc * 16;
    for (int tt = 0; tt < 16; ++tt) {
        const float* hp = hs + ((size_t)(t0 + tt) * kB + b) * kH;
        hl[tt][a]       = hp[a];
        hl[tt][a + 128] = hp[a + 128];
    }
    __syncthreads();
    float dot[16];
#pragma unroll
    for (int tt = 0; tt < 16; ++tt) dot[tt] = 0.f;
    for (int k = 0; k < kH; k += 4) {
        float w0 = W2[(k + 0) * kA2 + a];
        float w1 = W2[(k + 1) * kA2 + a];
        float w2 = W2[(k + 2) * kA2 + a];
        float w3 = W2[(k + 3) * kA2 + a];
#pragma unroll
        for (int tt = 0; tt < 16; ++tt) {
            float4 h4 = *(const float4*)&hl[tt][k];
            dot[tt] = fmaf(h4.x, w0, dot[tt]);
            dot[tt] = fmaf(h4.y, w1, dot[tt]);
            dot[tt] = fmaf(h4.z, w2, dot[tt]);
            dot[tt] = fmaf(h4.w, w3, dot[tt]);
        }
    }
    float bb = b2[a], uu = u2[a];
    int wave = a >> 6, lane = a & 63;
#pragma unroll
    for (int tt = 0; tt < 16; ++tt) {
        float v = fast_tanh(dot[tt] + bb) * uu;
#pragma unroll
        for (int m = 32; m; m >>= 1) v += __shfl_xor(v, m, 64);
        if (lane == 0) red[tt][wave] = v;
    }
    __syncthreads();
    if (a < 16) {
        float s = red[a][0] + red[a][1];
        a2w[(t0 + a) * kB + b] = __expf(s);
    }
}

// ---------------- Kernel 3b: weighted time-pool + linear head ----------------
__global__ __launch_bounds__(256) void att2b_kernel(
    const float* __restrict__ hs, const float* __restrict__ a2w,
    const float* __restrict__ Wl, const float* __restrict__ bl,
    float* __restrict__ out) {
    int b = blockIdx.x;
    int k = threadIdx.x;
    float acc = 0.f, den = 0.f;
    for (int t = 0; t < kT; ++t) {
        float e = a2w[t * kB + b];            // broadcast
        float h = hs[((size_t)t * kB + b) * kH + k];
        acc = fmaf(h, e, acc);
        den += e;
    }
    float v = (acc / den) * Wl[k];
#pragma unroll
    for (int m = 32; m; m >>= 1) v += __shfl_xor(v, m, 64);
    __shared__ float red[4];
    int wave = k >> 6, lane = k & 63;
    if (lane == 0) red[wave] = v;
    __syncthreads();
    if (k == 0) out[b] = red[0] + red[1] + red[2] + red[3] + bl[0];
}

extern "C" void kernel_launch(void* const* d_in, const int* in_sizes, int n_in,
                              void* d_out, int out_size, void* d_ws, size_t ws_size,
                              hipStream_t stream) {
    const float* inputs = (const float*)d_in[0];
    const float* W1   = (const float*)d_in[1];
    const float* b1   = (const float*)d_in[2];
    const float* u1   = (const float*)d_in[3];
    const float* W_ih = (const float*)d_in[4];
    const float* W_hh = (const float*)d_in[5];
    const float* b_ih = (const float*)d_in[6];
    const float* b_hh = (const float*)d_in[7];
    const float* h0   = (const float*)d_in[8];
    const float* c0   = (const float*)d_in[9];
    const float* W2   = (const float*)d_in[10];
    const float* b2   = (const float*)d_in[11];
    const float* u2   = (const float*)d_in[12];
    const float* Wl   = (const float*)d_in[13];
    const float* bl   = (const float*)d_in[14];
    float* out = (float*)d_out;

    char* ws = (char*)d_ws;
    float*    seq = (float*)(ws);                    // 64 KB  (T*B fp32)
    float*    a2w = (float*)(ws + (64 << 10));       // 64 KB  (T*B fp32)
    _Float16* WQ  = (_Float16*)(ws + (128 << 10));   // 512 KB (4H*H fp16, packed)
    unsigned* cnt = (unsigned*)(ws + (640 << 10));   // 64 KB  (T*B u32 flags)
    float*    hs  = (float*)(ws + (1 << 20));        // 16 MB  (T*B*H fp32)

    hipMemsetAsync(cnt, 0, kT * kB * sizeof(unsigned), stream);
    att1_kernel <<<kT * kB, 256, 0, stream>>>(inputs, W1, b1, u1, seq);
    wconv_kernel<<<512, 256, 0, stream>>>(W_hh, WQ);
    lstm_kernel <<<kB * kNPeer, 256, 0, stream>>>(seq, WQ, W_ih, b_ih, b_hh, h0, c0, hs, cnt);
    att2a_kernel<<<1024, 128, 0, stream>>>(hs, W2, b2, u2, a2w);
    att2b_kernel<<<kB, 256, 0, stream>>>(hs, a2w, Wl, bl, out);
}

// Round 9
// 1777.833 us; speedup vs baseline: 1.7019x; 1.7019x over previous
//
#include <hip/hip_runtime.h>
#include <hip/hip_fp16.h>

// Problem dims
constexpr int kT = 512, kB = 32, kD = 512, kH = 256, kA1 = 16, kA2 = 128;

typedef _Float16 h2_t __attribute__((ext_vector_type(2)));
typedef _Float16 h8_t __attribute__((ext_vector_type(8)));
typedef unsigned u4_t __attribute__((ext_vector_type(4)));

#if defined(__has_builtin)
#if __has_builtin(__builtin_amdgcn_fdot2)
#define HAVE_FDOT2 1
#endif
#endif

__device__ __forceinline__ float fast_tanh(float x) {
    // tanh(x) = 1 - 2/(exp(2x)+1); exp overflow -> inf -> 2/inf=0 -> 1 (correct)
    float e = __expf(2.0f * x);
    return 1.0f - 2.0f / (e + 1.0f);
}
__device__ __forceinline__ float fast_sig(float x) {
    return 1.0f / (1.0f + __expf(-x));
}

__device__ __forceinline__ float dot_pair(h2_t w, h2_t h, float acc) {
#if defined(HAVE_FDOT2)
    return __builtin_amdgcn_fdot2(w, h, acc, false);
#else
    acc = fmaf((float)w[0], (float)h[0], acc);
    return fmaf((float)w[1], (float)h[1], acc);
#endif
}

// ---------------- Kernel 1: attention over feature axis D -> seq (T,B) -------
__global__ __launch_bounds__(256) void att1_kernel(
    const float* __restrict__ x, const float* __restrict__ W1,
    const float* __restrict__ b1, const float* __restrict__ u1,
    float* __restrict__ seq) {
    int blk = blockIdx.x;                 // t*32 + b ; x offset = blk*kD
    int tid = threadIdx.x;
    const float* xp = x + (size_t)blk * kD;
    float x0 = xp[tid], x1 = xp[tid + 256];
    float s0 = 0.f, s1 = 0.f;
#pragma unroll
    for (int a = 0; a < kA1; ++a) {
        float w = W1[a], bb = b1[a], uu = u1[a];
        s0 += fast_tanh(fmaf(x0, w, bb)) * uu;
        s1 += fast_tanh(fmaf(x1, w, bb)) * uu;
    }
    float e0 = __expf(s0), e1 = __expf(s1);
    float se = e0 + e1;
    float sxe = fmaf(x0, e0, x1 * e1);
#pragma unroll
    for (int m = 32; m; m >>= 1) {
        se  += __shfl_xor(se,  m, 64);
        sxe += __shfl_xor(sxe, m, 64);
    }
    __shared__ float r_se[4], r_sxe[4];
    int wave = tid >> 6, lane = tid & 63;
    if (lane == 0) { r_se[wave] = se; r_sxe[wave] = sxe; }
    __syncthreads();
    if (tid == 0) {
        float S = r_se[0] + r_se[1] + r_se[2] + r_se[3];
        float X = r_sxe[0] + r_sxe[1] + r_sxe[2] + r_sxe[3];
        seq[blk] = X / S;
    }
}

// ------------- Kernel 1b: convert W_hh (4H,H) fp32 -> packed fp16 ------------
// Layout (half units): WQ[kk4*8192 + j*8 + q*2 + {0,1}] = W_hh[j][2*(4*kk4+q) + {0,1}]
// => as 16B vectors: W4[kk4*1024 + j] holds 8 consecutive k for row j.
__global__ __launch_bounds__(256) void wconv_kernel(
    const float* __restrict__ Whh, _Float16* __restrict__ WQ) {
    int idx = blockIdx.x * 256 + threadIdx.x;   // 0..131071 = j*128 + kk
    int j = idx >> 7, kk = idx & 127;
    int kk4 = kk >> 2, q = kk & 3;
    float a = Whh[j * kH + 2 * kk];
    float b = Whh[j * kH + 2 * kk + 1];
    _Float16* dst = WQ + ((size_t)kk4 * 8192 + j * 8 + q * 2);
    dst[0] = (_Float16)a;
    dst[1] = (_Float16)b;
}

// ---------------- Kernel 2: persistent per-batch LSTM ------------------------
// One workgroup (512 threads, 8 waves) per batch element. Thread j owns gate
// rows j and j+512 (PyTorch order: i=[0,H), f=[H,2H), g=[2H,3H), o=[3H,4H)
// => j<256 owns (i[j], g[j]); j>=256 owns (f[j-256], o[j-256])).
//
// Weight residency — THE AGPR SLAB (r8 post-mortem): every VGPR-residency
// attempt failed because the pre-RA scheduler polices ArchVGPR pressure
// (remat r2/r7, spill-to-L2-scratch r5/r6). On gfx950's unified register
// file the compiler never touches AGPRs in a non-MFMA kernel, so values
// bound to the "a" register class escape that heuristic entirely.
// k in [0,192) of both rows -> 192 AGPRs/thread via volatile
// v_accvgpr_write (cannot sink into loop) + volatile v_accvgpr_read in-loop
// (cannot be LICM-hoisted); k in [192,256) in a 128 KB LDS slab.
// Unified budget: 192 AGPR + ~48 arch = 240 <= 256 (launch_bounds(512,2)).
#define LSTM_BARRIER() asm volatile("s_waitcnt lgkmcnt(0)\n\ts_barrier" ::: "memory")

// h-pair broadcast: pair KK (h elements 2KK,2KK+1) via readlane. Lane select
// is uniform (SGPR) and constant-folds after unroll.
#define HPAIR(KK) __builtin_bit_cast(h2_t, (unsigned)__builtin_amdgcn_readlane( \
        ((KK) < 64) ? (int)hr0 : (int)hr1, (KK) & 63))

// 4 h-pairs (one h8_t weight vector) worth of fdot2, literal shuffle indices.
#define DOT4(W0, W1, KKB) do { \
    h2_t _hp0 = HPAIR((KKB) + 0); \
    acc0 = dot_pair(__builtin_shufflevector((W0), (W0), 0, 1), _hp0, acc0); \
    acc1 = dot_pair(__builtin_shufflevector((W1), (W1), 0, 1), _hp0, acc1); \
    h2_t _hp1 = HPAIR((KKB) + 1); \
    acc0 = dot_pair(__builtin_shufflevector((W0), (W0), 2, 3), _hp1, acc0); \
    acc1 = dot_pair(__builtin_shufflevector((W1), (W1), 2, 3), _hp1, acc1); \
    h2_t _hp2 = HPAIR((KKB) + 2); \
    acc0 = dot_pair(__builtin_shufflevector((W0), (W0), 4, 5), _hp2, acc0); \
    acc1 = dot_pair(__builtin_shufflevector((W1), (W1), 4, 5), _hp2, acc1); \
    h2_t _hp3 = HPAIR((KKB) + 3); \
    acc0 = dot_pair(__builtin_shufflevector((W0), (W0), 6, 7), _hp3, acc0); \
    acc1 = dot_pair(__builtin_shufflevector((W1), (W1), 6, 7), _hp3, acc1); \
} while (0)

__global__ __launch_bounds__(512, 2) void lstm_kernel(
    const float* __restrict__ seq, const _Float16* __restrict__ WQ,
    const float* __restrict__ W_ih, const float* __restrict__ b_ih,
    const float* __restrict__ b_hh, const float* __restrict__ h0,
    const float* __restrict__ c0, float* __restrict__ hs) {
    int b = blockIdx.x;
    int j = threadIdx.x;          // 0..511
    int lane = j & 63;

    __shared__ float seq_l[kT];                            // 2 KB
    __shared__ __align__(16) _Float16 wtail[8 * 1024 * 8]; // 128 KB: kk4=24..31
    __shared__ float fo[2][kH];                            // 2 KB (f and o gates)
    __shared__ __align__(8) _Float16 hl[kH];               // 512 B

    const u4_t* W4 = (const u4_t*)WQ;

    // ---- AGPR weight slab: kk4 = 0..23, rows j and j+512 (192 AGPRs) ----
    unsigned aw0[96], aw1[96];
#pragma unroll
    for (int kk4 = 0; kk4 < 24; ++kk4) {
        u4_t v0 = W4[kk4 * 1024 + j];
        u4_t v1 = W4[kk4 * 1024 + j + 512];
#pragma unroll
        for (int p = 0; p < 4; ++p) {
            asm volatile("v_accvgpr_write_b32 %0, %1" : "=a"(aw0[kk4 * 4 + p]) : "v"(v0[p]));
            asm volatile("v_accvgpr_write_b32 %0, %1" : "=a"(aw1[kk4 * 4 + p]) : "v"(v1[p]));
        }
    }

    for (int t = j; t < kT; t += 512) seq_l[t] = seq[t * kB + b];

    u4_t* wt4 = (u4_t*)wtail;
    // stage LDS weight tail (once): slices kk4 = 24..31, all 1024 rows
    for (int idx = j; idx < 8 * 1024; idx += 512)
        wt4[idx] = W4[(24 + (idx >> 10)) * 1024 + (idx & 1023)];

    int r0 = j, r1 = j + 512;
    float wih0 = W_ih[r0], wih1 = W_ih[r1];
    float bias0 = b_ih[r0] + b_hh[r0];
    float bias1 = b_ih[r1] + b_hh[r1];
    float c = 0.f;
    if (j < kH) {
        c = c0[b * kH + j];
        hl[j] = (_Float16)h0[b * kH + j];
    }
    LSTM_BARRIER();

    const unsigned* hl32 = (const unsigned*)hl;   // 128 packed fp16-pairs
    unsigned hr0 = hl32[lane];                    // pairs 0..63   (lane l -> pair l)
    unsigned hr1 = hl32[lane + 64];               // pairs 64..127

#pragma unroll 1
    for (int t = 0; t < kT; ++t) {
        float st = seq_l[t];
        float acc0 = fmaf(st, wih0, bias0);
        float acc1 = fmaf(st, wih1, bias1);

        // k in [0,192): weights read from the AGPR slab (volatile read ->
        // stays in-loop; 1 VALU op each), h broadcast via readlane.
#pragma unroll
        for (int kk = 0; kk < 96; ++kk) {
            unsigned t0, t1;
            asm volatile("v_accvgpr_read_b32 %0, %1" : "=v"(t0) : "a"(aw0[kk]));
            asm volatile("v_accvgpr_read_b32 %0, %1" : "=v"(t1) : "a"(aw1[kk]));
            h2_t hp = HPAIR(kk);
            acc0 = dot_pair(__builtin_bit_cast(h2_t, t0), hp, acc0);
            acc1 = dot_pair(__builtin_bit_cast(h2_t, t1), hp, acc1);
        }
        // k in [192,256): weights from the LDS slab (pairs 96..127 -> hr1
        // lanes 32..63). Unroll capped at 2 to bound in-flight b128 loads.
#pragma unroll 2
        for (int q = 0; q < 8; ++q) {
            h8_t w0 = __builtin_bit_cast(h8_t, wt4[q * 1024 + j]);
            h8_t w1 = __builtin_bit_cast(h8_t, wt4[q * 1024 + j + 512]);
            DOT4(w0, w1, 96 + q * 4);
        }

        if (j >= kH) {            // publish f and o gates
            fo[0][j - kH] = acc0;
            fo[1][j - kH] = acc1;
        }
        LSTM_BARRIER();

        if (j < kH) {             // i,g in registers; f,o from LDS
            float ig = fast_sig(acc0);
            float gg = fast_tanh(acc1);
            float fg = fast_sig(fo[0][j]);
            float og = fast_sig(fo[1][j]);
            c = fmaf(fg, c, ig * gg);
            float h = og * fast_tanh(c);
            hs[(size_t)t * (kB * kH) + b * kH + j] = h;   // store floats, never drained
            hl[j] = (_Float16)h;
        }
        LSTM_BARRIER();

        hr0 = hl32[lane];
        hr1 = hl32[lane + 64];
    }
}

// ---------------- Kernel 3a: attention-2 scores e2 (T,B) ---------------------
// Block = (b, chunk of 16 t). 128 threads, thread a owns attention unit a.
__global__ __launch_bounds__(128) void att2a_kernel(
    const float* __restrict__ hs, const float* __restrict__ W2,
    const float* __restrict__ b2, const float* __restrict__ u2,
    float* __restrict__ a2w) {
    int b  = blockIdx.x & 31;
    int tc = blockIdx.x >> 5;   // 0..31
    int a  = threadIdx.x;       // 0..127
    __shared__ __align__(16) float hl[16][kH];
    __shared__ float red[16][2];
    int t0 = tc * 16;
    for (int tt = 0; tt < 16; ++tt) {
        const float* hp = hs + ((size_t)(t0 + tt) * kB + b) * kH;
        hl[tt][a]       = hp[a];
        hl[tt][a + 128] = hp[a + 128];
    }
    __syncthreads();
    float dot[16];
#pragma unroll
    for (int tt = 0; tt < 16; ++tt) dot[tt] = 0.f;
    for (int k = 0; k < kH; k += 4) {
        float w0 = W2[(k + 0) * kA2 + a];
        float w1 = W2[(k + 1) * kA2 + a];
        float w2 = W2[(k + 2) * kA2 + a];
        float w3 = W2[(k + 3) * kA2 + a];
#pragma unroll
        for (int tt = 0; tt < 16; ++tt) {
            float4 h4 = *(const float4*)&hl[tt][k];
            dot[tt] = fmaf(h4.x, w0, dot[tt]);
            dot[tt] = fmaf(h4.y, w1, dot[tt]);
            dot[tt] = fmaf(h4.z, w2, dot[tt]);
            dot[tt] = fmaf(h4.w, w3, dot[tt]);
        }
    }
    float bb = b2[a], uu = u2[a];
    int wave = a >> 6, lane = a & 63;
#pragma unroll
    for (int tt = 0; tt < 16; ++tt) {
        float v = fast_tanh(dot[tt] + bb) * uu;
#pragma unroll
        for (int m = 32; m; m >>= 1) v += __shfl_xor(v, m, 64);
        if (lane == 0) red[tt][wave] = v;
    }
    __syncthreads();
    if (a < 16) {
        float s = red[a][0] + red[a][1];
        a2w[(t0 + a) * kB + b] = __expf(s);
    }
}

// ---------------- Kernel 3b: weighted time-pool + linear head ----------------
__global__ __launch_bounds__(256) void att2b_kernel(
    const float* __restrict__ hs, const float* __restrict__ a2w,
    const float* __restrict__ Wl, const float* __restrict__ bl,
    float* __restrict__ out) {
    int b = blockIdx.x;
    int k = threadIdx.x;
    float acc = 0.f, den = 0.f;
    for (int t = 0; t < kT; ++t) {
        float e = a2w[t * kB + b];            // broadcast
        float h = hs[((size_t)t * kB + b) * kH + k];
        acc = fmaf(h, e, acc);
        den += e;
    }
    float v = (acc / den) * Wl[k];
#pragma unroll
    for (int m = 32; m; m >>= 1) v += __shfl_xor(v, m, 64);
    __shared__ float red[4];
    int wave = k >> 6, lane = k & 63;
    if (lane == 0) red[wave] = v;
    __syncthreads();
    if (k == 0) out[b] = red[0] + red[1] + red[2] + red[3] + bl[0];
}

extern "C" void kernel_launch(void* const* d_in, const int* in_sizes, int n_in,
                              void* d_out, int out_size, void* d_ws, size_t ws_size,
                              hipStream_t stream) {
    const float* inputs = (const float*)d_in[0];
    const float* W1   = (const float*)d_in[1];
    const float* b1   = (const float*)d_in[2];
    const float* u1   = (const float*)d_in[3];
    const float* W_ih = (const float*)d_in[4];
    const float* W_hh = (const float*)d_in[5];
    const float* b_ih = (const float*)d_in[6];
    const float* b_hh = (const float*)d_in[7];
    const float* h0   = (const float*)d_in[8];
    const float* c0   = (const float*)d_in[9];
    const float* W2   = (const float*)d_in[10];
    const float* b2   = (const float*)d_in[11];
    const float* u2   = (const float*)d_in[12];
    const float* Wl   = (const float*)d_in[13];
    const float* bl   = (const float*)d_in[14];
    float* out = (float*)d_out;

    char* ws = (char*)d_ws;
    float*    seq = (float*)(ws);                    // 64 KB  (T*B fp32)
    float*    a2w = (float*)(ws + (64 << 10));       // 64 KB  (T*B fp32)
    _Float16* WQ  = (_Float16*)(ws + (128 << 10));   // 512 KB (4H*H fp16, packed)
    float*    hs  = (float*)(ws + (1 << 20));        // 16 MB  (T*B*H fp32)

    att1_kernel <<<kT * kB, 256, 0, stream>>>(inputs, W1, b1, u1, seq);
    wconv_kernel<<<512, 256, 0, stream>>>(W_hh, WQ);
    lstm_kernel <<<kB, 512, 0, stream>>>(seq, WQ, W_ih, b_ih, b_hh, h0, c0, hs);
    att2a_kernel<<<1024, 128, 0, stream>>>(hs, W2, b2, u2, a2w);
    att2b_kernel<<<kB, 256, 0, stream>>>(hs, a2w, Wl, bl, out);
}